// Round 1
// baseline (347.124 us; speedup 1.0000x reference)
//
#include <hip/hip_runtime.h>
#include <hip/hip_bf16.h>
#include <stdint.h>

typedef unsigned short u16;
typedef __attribute__((ext_vector_type(8))) short bf16x8;
typedef __attribute__((ext_vector_type(4))) float f32x4;

#define DEVI static __device__ __forceinline__

// problem constants
constexpr int Bc = 4, Sc = 2048, Hc = 16;

DEVI u16 f2bf(float f) {
  __hip_bfloat16 h = __float2bfloat16(f);
  u16 u; __builtin_memcpy(&u, &h, 2);
  return u;
}

DEVI void gl_lds16(const void* g, void* l) {
  __builtin_amdgcn_global_load_lds(
      (__attribute__((address_space(1))) void*)(uintptr_t)g,
      (__attribute__((address_space(3))) void*)l, 16, 0, 0);
}

// ---------------- cast x (f32 -> bf16), 4 elems/thread ----------------
__global__ __launch_bounds__(256) void cast_x_kernel(const float* __restrict__ x,
                                                     u16* __restrict__ xb, int n4) {
  int i = blockIdx.x * 256 + threadIdx.x;
  if (i >= n4) return;
  float4 a = reinterpret_cast<const float4*>(x)[i];
  uint2 r;
  r.x = (uint32_t)f2bf(a.x) | ((uint32_t)f2bf(a.y) << 16);
  r.y = (uint32_t)f2bf(a.z) | ((uint32_t)f2bf(a.w) << 16);
  reinterpret_cast<uint2*>(xb)[i] = r;
}

// ---------------- cast + transpose W: W[k][n] f32 -> wt[t][n][k] bf16 ----------------
__global__ __launch_bounds__(256) void cast_wt_kernel(const float* __restrict__ Wq,
                                                      const float* __restrict__ Wk,
                                                      const float* __restrict__ Wv,
                                                      u16* __restrict__ wt) {
  __shared__ float ls[64][66];
  int blk = blockIdx.x;              // t*256 + kb*16 + nb
  int t = blk >> 8, rem = blk & 255;
  int kb = rem >> 4, nb = rem & 15;
  const float* W = (t == 0) ? Wq : (t == 1) ? Wk : Wv;
  int tid = threadIdx.x;
#pragma unroll
  for (int i = 0; i < 16; ++i) {
    int idx = tid + i * 256;
    int r = idx >> 6, c = idx & 63;
    ls[r][c] = W[(size_t)(kb * 64 + r) * 1024 + nb * 64 + c];
  }
  __syncthreads();
  u16* wto = wt + (size_t)t * 1024 * 1024;
#pragma unroll
  for (int i = 0; i < 16; ++i) {
    int idx = tid + i * 256;
    int n = idx >> 6, k = idx & 63;
    wto[(size_t)(nb * 64 + n) * 1024 + kb * 64 + k] = f2bf(ls[k][n]);
  }
}

// ---------------- fused QKV GEMM: [8192x1024] x [1024x3072] -> Q,K,V [BH][S][D] bf16 --
__global__ __launch_bounds__(256) void qkv_gemm_kernel(const u16* __restrict__ xb,
                                                       const u16* __restrict__ wt,
                                                       const float* __restrict__ bq,
                                                       const float* __restrict__ bk,
                                                       const float* __restrict__ bv,
                                                       u16* __restrict__ qb,
                                                       u16* __restrict__ kbuf,
                                                       u16* __restrict__ vbuf) {
  __shared__ __align__(16) u16 Ab[128][64];
  __shared__ __align__(16) u16 Bb[128][64];
  int tile = blockIdx.x;
  int tn = tile % 24, tm = tile / 24;
  int m0 = tm * 128, n0 = tn * 128;
  int tid = threadIdx.x;
  int w = tid >> 6, lane = tid & 63;
  int wr = w >> 1, wc = w & 1;
  f32x4 acc[4][4] = {};
  int arow = wr * 64 + (lane & 15);
  int brow = wc * 64 + (lane & 15);
  int kfrag = (lane >> 4) * 8;
  for (int kt = 0; kt < 16; ++kt) {
    int k0 = kt * 64;
#pragma unroll
    for (int i = 0; i < 4; ++i) {
      int r = 32 * w + 8 * i + (lane >> 3);
      gl_lds16(xb + (size_t)(m0 + r) * 1024 + k0 + (lane & 7) * 8, &Ab[32 * w + 8 * i][0]);
      gl_lds16(wt + (size_t)(n0 + r) * 1024 + k0 + (lane & 7) * 8, &Bb[32 * w + 8 * i][0]);
    }
    __syncthreads();
#pragma unroll
    for (int kk = 0; kk < 2; ++kk) {
      bf16x8 af[4], bfr[4];
#pragma unroll
      for (int mi = 0; mi < 4; ++mi)
        af[mi] = *(const bf16x8*)&Ab[arow + mi * 16][kk * 32 + kfrag];
#pragma unroll
      for (int ni = 0; ni < 4; ++ni)
        bfr[ni] = *(const bf16x8*)&Bb[brow + ni * 16][kk * 32 + kfrag];
#pragma unroll
      for (int mi = 0; mi < 4; ++mi)
#pragma unroll
        for (int ni = 0; ni < 4; ++ni)
          acc[mi][ni] = __builtin_amdgcn_mfma_f32_16x16x32_bf16(af[mi], bfr[ni], acc[mi][ni], 0, 0, 0);
    }
    __syncthreads();
  }
  // epilogue: bias + scatter into [B][H][S][D] bf16
  int tsel = n0 >> 10;
  int nl0 = n0 & 1023;
  const float* bias = (tsel == 0) ? bq : (tsel == 1) ? bk : bv;
  u16* outp = (tsel == 0) ? qb : (tsel == 1) ? kbuf : vbuf;
#pragma unroll
  for (int ni = 0; ni < 4; ++ni) {
    int ncol = nl0 + wc * 64 + ni * 16 + (lane & 15);
    float bia = bias[ncol];
    int h = ncol >> 6, d = ncol & 63;
#pragma unroll
    for (int mi = 0; mi < 4; ++mi) {
#pragma unroll
      for (int jj = 0; jj < 4; ++jj) {
        int m = m0 + wr * 64 + mi * 16 + (lane >> 4) * 4 + jj;
        int b = m >> 11, s = m & 2047;
        outp[(((size_t)(b * Hc + h) * Sc + s) << 6) + d] = f2bf(acc[mi][ni][jj] + bia);
      }
    }
  }
}

// ---------------- V [BH][S][D] -> Vt [BH][D][S] ----------------
__global__ __launch_bounds__(256) void vtrans_kernel(const u16* __restrict__ vbuf,
                                                     u16* __restrict__ vtb) {
  __shared__ u16 ls[64][66];
  int bid = blockIdx.x;
  int sb = bid & 31, bh = bid >> 5;
  int tid = threadIdx.x;
  const u16* src = vbuf + ((size_t)bh * Sc + sb * 64) * 64;
#pragma unroll
  for (int i = 0; i < 16; ++i) {
    int idx = tid + i * 256;
    ls[idx >> 6][idx & 63] = src[idx];
  }
  __syncthreads();
  u16* dst = vtb + (size_t)bh * 64 * Sc + sb * 64;
#pragma unroll
  for (int i = 0; i < 16; ++i) {
    int idx = tid + i * 256;
    int d = idx >> 6, s = idx & 63;
    dst[(size_t)d * Sc + s] = ls[s][d];
  }
}

// ---------------- flash attention ----------------
// grid: bh*16 q-blocks; block: 4 waves x 32 queries each; kv-blocks of 64
__global__ __launch_bounds__(256) void attn_kernel(const u16* __restrict__ qb,
                                                   const u16* __restrict__ kbuf,
                                                   const u16* __restrict__ vtb,
                                                   const int* __restrict__ mask,
                                                   float* __restrict__ out) {
  __shared__ __align__(16) u16 Klds[64 * 64];      // swizzled [key][d]
  __shared__ __align__(16) u16 Vlds[64 * 64];      // swizzled [d][key]
  __shared__ __align__(16) u16 Plds[4][32 * 64];   // per-wave swizzled [q][key]
  __shared__ float mlds[64];
  int bid = blockIdx.x;
  int qblk = bid & 15, bh = bid >> 4;
  int b = bh >> 4, h = bh & 15;
  int tid = threadIdx.x, w = tid >> 6, lane = tid & 63;
  int qw = qblk * 128 + w * 32;
  const u16* Qp = qb + (size_t)bh * Sc * 64;
  const u16* Kp = kbuf + (size_t)bh * Sc * 64;
  const u16* Vp = vtb + (size_t)bh * 64 * Sc;
  const float SCLOG2 = 0.18033688011112042f;  // log2(e)/sqrt(D), D=64

  // Q fragments held in registers for the whole pass
  bf16x8 qf[2][2];
#pragma unroll
  for (int qt = 0; qt < 2; ++qt)
#pragma unroll
    for (int kk = 0; kk < 2; ++kk)
      qf[qt][kk] = *(const bf16x8*)(Qp + (size_t)(qw + qt * 16 + (lane & 15)) * 64 +
                                    kk * 32 + (lane >> 4) * 8);

  f32x4 yacc[2][4] = {};
  float mrow[2][4], lrow[2][4];
#pragma unroll
  for (int qt = 0; qt < 2; ++qt)
#pragma unroll
    for (int jj = 0; jj < 4; ++jj) { mrow[qt][jj] = -1e30f; lrow[qt][jj] = 0.f; }

  for (int kt = 0; kt < 32; ++kt) {
    int k0 = kt * 64;
    // stage K tile and Vt tile (inverse-swizzled global source, linear LDS dest)
#pragma unroll
    for (int i = 0; i < 2; ++i) {
      int r = 16 * w + 8 * i + (lane >> 3);
      int lc = ((lane & 7) ^ (r & 7)) * 16;
      gl_lds16((const char*)Kp + (size_t)(k0 + r) * 128 + lc, &Klds[(16 * w + 8 * i) * 64]);
      gl_lds16((const char*)Vp + (size_t)r * (Sc * 2) + (size_t)k0 * 2 + lc,
               &Vlds[(16 * w + 8 * i) * 64]);
    }
    if (w == 3) {
      int mv = mask[b * Sc + k0 + lane];
      mlds[lane] = mv ? 0.f : -1e30f;
    }
    __syncthreads();

    // S = Q K^T   (A=Q regs, B-frag from swizzled Klds)
    f32x4 sacc[2][4] = {};
#pragma unroll
    for (int kk = 0; kk < 2; ++kk) {
      bf16x8 kf[4];
#pragma unroll
      for (int ct = 0; ct < 4; ++ct) {
        int row = ct * 16 + (lane & 15);
        int lc = (kk * 64 + (lane >> 4) * 16) ^ ((row & 7) << 4);
        kf[ct] = *(const bf16x8*)((const char*)Klds + row * 128 + lc);
      }
#pragma unroll
      for (int qt = 0; qt < 2; ++qt)
#pragma unroll
        for (int ct = 0; ct < 4; ++ct)
          sacc[qt][ct] =
              __builtin_amdgcn_mfma_f32_16x16x32_bf16(qf[qt][kk], kf[ct], sacc[qt][ct], 0, 0, 0);
    }

    float madd[4];
#pragma unroll
    for (int ct = 0; ct < 4; ++ct) madd[ct] = mlds[ct * 16 + (lane & 15)];

    // online softmax (base-2 domain; rows = (lane>>4)*4+jj, cols = keys across 16 lanes)
#pragma unroll
    for (int qt = 0; qt < 2; ++qt) {
      float pv[4][4];
      float alpha[4];
#pragma unroll
      for (int jj = 0; jj < 4; ++jj) {
        float mx = -1e30f;
#pragma unroll
        for (int ct = 0; ct < 4; ++ct) {
          float tval = (sacc[qt][ct][jj] + madd[ct]) * SCLOG2;
          pv[ct][jj] = tval;
          mx = fmaxf(mx, tval);
        }
#pragma unroll
        for (int off = 1; off < 16; off <<= 1) mx = fmaxf(mx, __shfl_xor(mx, off, 64));
        float mnew = fmaxf(mrow[qt][jj], mx);
        alpha[jj] = exp2f(mrow[qt][jj] - mnew);
        mrow[qt][jj] = mnew;
        float rs = 0.f;
#pragma unroll
        for (int ct = 0; ct < 4; ++ct) {
          float p = exp2f(pv[ct][jj] - mnew);
          pv[ct][jj] = p;
          rs += p;
        }
#pragma unroll
        for (int off = 1; off < 16; off <<= 1) rs += __shfl_xor(rs, off, 64);
        lrow[qt][jj] = lrow[qt][jj] * alpha[jj] + rs;
      }
#pragma unroll
      for (int dt = 0; dt < 4; ++dt)
#pragma unroll
        for (int jj = 0; jj < 4; ++jj) yacc[qt][dt][jj] *= alpha[jj];
      // write P to per-wave LDS (swizzled) for the layout transpose
#pragma unroll
      for (int ct = 0; ct < 4; ++ct)
#pragma unroll
        for (int jj = 0; jj < 4; ++jj) {
          int ql = qt * 16 + (lane >> 4) * 4 + jj;
          int pc = ((ct * 16 + (lane & 15)) * 2) ^ ((ql & 7) << 4);
          *(u16*)((char*)&Plds[w][0] + ql * 128 + pc) = f2bf(pv[ct][jj]);
        }
    }
    __syncthreads();

    // Y += P V   (A-frag from swizzled Plds, B-frag from swizzled Vlds = V^T)
#pragma unroll
    for (int kk2 = 0; kk2 < 2; ++kk2) {
      bf16x8 pf[2];
#pragma unroll
      for (int qt = 0; qt < 2; ++qt) {
        int q = qt * 16 + (lane & 15);
        int lc = (kk2 * 64 + (lane >> 4) * 16) ^ ((q & 7) << 4);
        pf[qt] = *(const bf16x8*)((const char*)&Plds[w][0] + q * 128 + lc);
      }
      bf16x8 vf[4];
#pragma unroll
      for (int dt = 0; dt < 4; ++dt) {
        int row = dt * 16 + (lane & 15);
        int lc = (kk2 * 64 + (lane >> 4) * 16) ^ ((row & 7) << 4);
        vf[dt] = *(const bf16x8*)((const char*)Vlds + row * 128 + lc);
      }
#pragma unroll
      for (int qt = 0; qt < 2; ++qt)
#pragma unroll
        for (int dt = 0; dt < 4; ++dt)
          yacc[qt][dt] = __builtin_amdgcn_mfma_f32_16x16x32_bf16(pf[qt], vf[dt], yacc[qt][dt], 0, 0, 0);
    }
    __syncthreads();
  }

  // epilogue: y / l -> out[b][s][h*64+d] f32
#pragma unroll
  for (int qt = 0; qt < 2; ++qt) {
#pragma unroll
    for (int jj = 0; jj < 4; ++jj) {
      float rl = 1.0f / lrow[qt][jj];
      int s = qw + qt * 16 + (lane >> 4) * 4 + jj;
#pragma unroll
      for (int dt = 0; dt < 4; ++dt) {
        int d = dt * 16 + (lane & 15);
        out[((size_t)(b * Sc + s) << 10) + h * 64 + d] = yacc[qt][dt][jj] * rl;
      }
    }
  }
}

extern "C" void kernel_launch(void* const* d_in, const int* in_sizes, int n_in,
                              void* d_out, int out_size, void* d_ws, size_t ws_size,
                              hipStream_t stream) {
  const float* x  = (const float*)d_in[0];
  const int* mask = (const int*)d_in[1];
  const float* Wq = (const float*)d_in[2];
  const float* bq = (const float*)d_in[3];
  const float* Wk = (const float*)d_in[4];
  const float* bk = (const float*)d_in[5];
  const float* Wv = (const float*)d_in[6];
  const float* bv = (const float*)d_in[7];
  float* out = (float*)d_out;

  char* ws = (char*)d_ws;
  const size_t SZ_XB = (size_t)8192 * 1024 * 2;      // 16 MiB bf16 x
  const size_t SZ_WT = (size_t)3 * 1024 * 1024 * 2;  // 6 MiB bf16 W^T
  const size_t SZ_T  = (size_t)8192 * 1024 * 2;      // 16 MiB each Q/K/V/Vt
  u16* xb  = (u16*)ws;
  u16* wt  = (u16*)(ws + SZ_XB);
  u16* qb  = (u16*)(ws + SZ_XB + SZ_WT);
  u16* kb  = (u16*)(ws + SZ_XB + SZ_WT + SZ_T);
  u16* vb  = (u16*)(ws + SZ_XB + SZ_WT + 2 * SZ_T);
  u16* vtb = (u16*)(ws + SZ_XB + SZ_WT + 3 * SZ_T);

  cast_x_kernel<<<8192, 256, 0, stream>>>(x, xb, 8192 * 1024 / 4);
  cast_wt_kernel<<<768, 256, 0, stream>>>(Wq, Wk, Wv, wt);
  qkv_gemm_kernel<<<1536, 256, 0, stream>>>(xb, wt, bq, bk, bv, qb, kb, vb);
  vtrans_kernel<<<2048, 256, 0, stream>>>(vb, vtb);
  attn_kernel<<<1024, 256, 0, stream>>>(qb, kb, vtb, mask, out);
}

// Round 3
// 338.752 us; speedup vs baseline: 1.0247x; 1.0247x over previous
//
#include <hip/hip_runtime.h>
#include <hip/hip_bf16.h>
#include <stdint.h>

typedef unsigned short u16;
typedef __attribute__((ext_vector_type(8))) short bf16x8;
typedef __attribute__((ext_vector_type(4))) float f32x4;
typedef __attribute__((ext_vector_type(16))) float f32x16;

#define DEVI static __device__ __forceinline__

// problem constants
constexpr int Bc = 4, Sc = 2048, Hc = 16;

DEVI u16 f2bf(float f) {
  __hip_bfloat16 h = __float2bfloat16(f);
  u16 u; __builtin_memcpy(&u, &h, 2);
  return u;
}

// pack two floats -> one u32 of 2 bf16 (lo = a, hi = b); compiler emits cvt_pk
DEVI uint32_t pk2(float a, float b) {
  float2 f2; f2.x = a; f2.y = b;
  __hip_bfloat162 h = __float22bfloat162_rn(f2);
  uint32_t r; __builtin_memcpy(&r, &h, 4);
  return r;
}

DEVI void gl_lds16(const void* g, void* l) {
  __builtin_amdgcn_global_load_lds(
      (__attribute__((address_space(1))) void*)(uintptr_t)g,
      (__attribute__((address_space(3))) void*)l, 16, 0, 0);
}

// ---------------- cast x (f32 -> bf16), 4 elems/thread ----------------
__global__ __launch_bounds__(256) void cast_x_kernel(const float* __restrict__ x,
                                                     u16* __restrict__ xb, int n4) {
  int i = blockIdx.x * 256 + threadIdx.x;
  if (i >= n4) return;
  float4 a = reinterpret_cast<const float4*>(x)[i];
  uint2 r;
  r.x = (uint32_t)f2bf(a.x) | ((uint32_t)f2bf(a.y) << 16);
  r.y = (uint32_t)f2bf(a.z) | ((uint32_t)f2bf(a.w) << 16);
  reinterpret_cast<uint2*>(xb)[i] = r;
}

// ---------------- cast + transpose W: W[k][n] f32 -> wt[t][n][k] bf16 ----------------
__global__ __launch_bounds__(256) void cast_wt_kernel(const float* __restrict__ Wq,
                                                      const float* __restrict__ Wk,
                                                      const float* __restrict__ Wv,
                                                      u16* __restrict__ wt) {
  __shared__ float ls[64][66];
  int blk = blockIdx.x;              // t*256 + kb*16 + nb
  int t = blk >> 8, rem = blk & 255;
  int kb = rem >> 4, nb = rem & 15;
  const float* W = (t == 0) ? Wq : (t == 1) ? Wk : Wv;
  int tid = threadIdx.x;
#pragma unroll
  for (int i = 0; i < 16; ++i) {
    int idx = tid + i * 256;
    int r = idx >> 6, c = idx & 63;
    ls[r][c] = W[(size_t)(kb * 64 + r) * 1024 + nb * 64 + c];
  }
  __syncthreads();
  u16* wto = wt + (size_t)t * 1024 * 1024;
#pragma unroll
  for (int i = 0; i < 16; ++i) {
    int idx = tid + i * 256;
    int n = idx >> 6, k = idx & 63;
    wto[(size_t)(nb * 64 + n) * 1024 + kb * 64 + k] = f2bf(ls[k][n]);
  }
}

// ---------------- fused QKV GEMM: [8192x1024] x [1024x3072] -> Q,K,V [BH][S][D] bf16 --
__global__ __launch_bounds__(256) void qkv_gemm_kernel(const u16* __restrict__ xb,
                                                       const u16* __restrict__ wt,
                                                       const float* __restrict__ bq,
                                                       const float* __restrict__ bk,
                                                       const float* __restrict__ bv,
                                                       u16* __restrict__ qb,
                                                       u16* __restrict__ kbuf,
                                                       u16* __restrict__ vbuf) {
  __shared__ __align__(16) u16 Ab[128][64];
  __shared__ __align__(16) u16 Bb[128][64];
  int tile = blockIdx.x;
  int tn = tile % 24, tm = tile / 24;
  int m0 = tm * 128, n0 = tn * 128;
  int tid = threadIdx.x;
  int w = tid >> 6, lane = tid & 63;
  int wr = w >> 1, wc = w & 1;
  f32x4 acc[4][4] = {};
  int arow = wr * 64 + (lane & 15);
  int brow = wc * 64 + (lane & 15);
  int kfrag = (lane >> 4) * 8;
  for (int kt = 0; kt < 16; ++kt) {
    int k0 = kt * 64;
#pragma unroll
    for (int i = 0; i < 4; ++i) {
      int r = 32 * w + 8 * i + (lane >> 3);
      gl_lds16(xb + (size_t)(m0 + r) * 1024 + k0 + (lane & 7) * 8, &Ab[32 * w + 8 * i][0]);
      gl_lds16(wt + (size_t)(n0 + r) * 1024 + k0 + (lane & 7) * 8, &Bb[32 * w + 8 * i][0]);
    }
    __syncthreads();
#pragma unroll
    for (int kk = 0; kk < 2; ++kk) {
      bf16x8 af[4], bfr[4];
#pragma unroll
      for (int mi = 0; mi < 4; ++mi)
        af[mi] = *(const bf16x8*)&Ab[arow + mi * 16][kk * 32 + kfrag];
#pragma unroll
      for (int ni = 0; ni < 4; ++ni)
        bfr[ni] = *(const bf16x8*)&Bb[brow + ni * 16][kk * 32 + kfrag];
#pragma unroll
      for (int mi = 0; mi < 4; ++mi)
#pragma unroll
        for (int ni = 0; ni < 4; ++ni)
          acc[mi][ni] = __builtin_amdgcn_mfma_f32_16x16x32_bf16(af[mi], bfr[ni], acc[mi][ni], 0, 0, 0);
    }
    __syncthreads();
  }
  // epilogue: bias + scatter into [B][H][S][D] bf16
  int tsel = n0 >> 10;
  int nl0 = n0 & 1023;
  const float* bias = (tsel == 0) ? bq : (tsel == 1) ? bk : bv;
  u16* outp = (tsel == 0) ? qb : (tsel == 1) ? kbuf : vbuf;
#pragma unroll
  for (int ni = 0; ni < 4; ++ni) {
    int ncol = nl0 + wc * 64 + ni * 16 + (lane & 15);
    float bia = bias[ncol];
    int h = ncol >> 6, d = ncol & 63;
#pragma unroll
    for (int mi = 0; mi < 4; ++mi) {
#pragma unroll
      for (int jj = 0; jj < 4; ++jj) {
        int m = m0 + wr * 64 + mi * 16 + (lane >> 4) * 4 + jj;
        int b = m >> 11, s = m & 2047;
        outp[(((size_t)(b * Hc + h) * Sc + s) << 6) + d] = f2bf(acc[mi][ni][jj] + bia);
      }
    }
  }
}

// ---------------- V [BH][S][D] -> Vt [BH][D][S] ----------------
__global__ __launch_bounds__(256) void vtrans_kernel(const u16* __restrict__ vbuf,
                                                     u16* __restrict__ vtb) {
  __shared__ u16 ls[64][66];
  int bid = blockIdx.x;
  int sb = bid & 31, bh = bid >> 5;
  int tid = threadIdx.x;
  const u16* src = vbuf + ((size_t)bh * Sc + sb * 64) * 64;
#pragma unroll
  for (int i = 0; i < 16; ++i) {
    int idx = tid + i * 256;
    ls[idx >> 6][idx & 63] = src[idx];
  }
  __syncthreads();
  u16* dst = vtb + (size_t)bh * 64 * Sc + sb * 64;
#pragma unroll
  for (int i = 0; i < 16; ++i) {
    int idx = tid + i * 256;
    int d = idx >> 6, s = idx & 63;
    dst[(size_t)d * Sc + s] = ls[s][d];
  }
}

// ---------------- flash attention, swapped-QK^T 32x32x16 structure ----------------
// grid: 1024 blocks = 16 qblocks x 64 bh (bh = bid&63 -> same-bh blocks share XCD).
// block: 4 waves x 32 queries. Per wave: lane owns one query column; softmax fully
// in-register; P->bf16 A-frags via pack + shfl_xor(32) + select (primitive-safe).
__global__ __launch_bounds__(256) void attn_kernel(const u16* __restrict__ qb,
                                                   const u16* __restrict__ kbuf,
                                                   const u16* __restrict__ vtb,
                                                   const int* __restrict__ mask,
                                                   float* __restrict__ out) {
  __shared__ float mlds[2048];
  int bid = blockIdx.x;
  int bh = bid & 63, qblk = bid >> 6;
  int b = bh >> 4, h = bh & 15;
  int tid = threadIdx.x, w = tid >> 6, lane = tid & 63;
  int col = lane & 31, hi = lane >> 5;
  int qw = qblk * 128 + w * 32;
  const u16* Qp = qb + (size_t)bh * Sc * 64;
  const u16* Kp = kbuf + (size_t)bh * Sc * 64;
  const u16* Vp = vtb + (size_t)bh * 64 * Sc;

  // mask -> prescaled additive table (exact under online softmax)
  for (int i = tid; i < Sc; i += 256)
    mlds[i] = mask[b * Sc + i] ? 0.f : -1e30f;
  __syncthreads();

  const float SCLOG2 = 0.18033688011112042f;  // log2(e)/sqrt(D)

  // Q as B-fragments: lane holds Q[q=col][dc*16 + hi*8 + j]
  bf16x8 qf[4];
#pragma unroll
  for (int dc = 0; dc < 4; ++dc)
    qf[dc] = *(const bf16x8*)(Qp + (size_t)(qw + col) * 64 + dc * 16 + hi * 8);

  f32x16 yacc0 = {}, yacc1 = {};
  float m = -1e30f, l = 0.f;

#pragma unroll 2
  for (int kt = 0; kt < 64; ++kt) {
    if ((kt & 1) == 0) __builtin_amdgcn_s_barrier();  // loose lockstep for L1 reuse
    int k0 = kt * 32;
    // K as A-fragments (rows = keys), V^T as B-fragments (cols = d)
    bf16x8 kf[4], vf[4];
#pragma unroll
    for (int dc = 0; dc < 4; ++dc)
      kf[dc] = *(const bf16x8*)(Kp + (size_t)(k0 + col) * 64 + dc * 16 + hi * 8);
#pragma unroll
    for (int kc = 0; kc < 2; ++kc)
#pragma unroll
      for (int dn = 0; dn < 2; ++dn)
        vf[kc * 2 + dn] =
            *(const bf16x8*)(Vp + (size_t)(dn * 32 + col) * Sc + k0 + kc * 16 + hi * 8);
    f32x4 mg[4];
#pragma unroll
    for (int g = 0; g < 4; ++g)
      mg[g] = *(const f32x4*)&mlds[k0 + 8 * g + 4 * hi];

    // S[key][q] = K . Q^T : lane holds 16 key-rows for query col
    f32x16 s = {};
#pragma unroll
    for (int dc = 0; dc < 4; ++dc)
      s = __builtin_amdgcn_mfma_f32_32x32x16_bf16(kf[dc], qf[dc], s, 0, 0, 0);

    // online softmax, in-register (key r -> (r&3)+8*(r>>2)+4*hi)
    float p[16];
    float tmax = -1e30f;
#pragma unroll
    for (int r = 0; r < 16; ++r) {
      p[r] = __builtin_fmaf(s[r], SCLOG2, mg[r >> 2][r & 3]);
      tmax = fmaxf(tmax, p[r]);
    }
    tmax = fmaxf(tmax, __shfl_xor(tmax, 32));
    if (!__all(tmax <= m + 3.0f)) {  // defer-rescale (T13)
      float mnew = fmaxf(m, tmax);
      float alpha = exp2f(m - mnew);
      m = mnew;
      l *= alpha;
#pragma unroll
      for (int r = 0; r < 16; ++r) {
        float ar = __shfl(alpha, (r & 3) + 8 * (r >> 2) + 4 * hi);
        yacc0[r] *= ar;
        yacc1[r] *= ar;
      }
    }
    float ls = 0.f;
#pragma unroll
    for (int r = 0; r < 16; ++r) {
      p[r] = exp2f(p[r] - m);
      ls += p[r];
    }
    ls += __shfl_xor(ls, 32);
    l += ls;

    // P -> bf16 A-fragments. Lane owns P[q=col][16 keys]; A-frag needs
    // P[q=col][key = kc*16 + hi*8 + j]. Cross-half exchange via shfl_xor(32)
    // + select (direction-safe, unlike permlane32_swap operand guessing).
    uint32_t pw[8];
#pragma unroll
    for (int i = 0; i < 8; ++i) pw[i] = pk2(p[2 * i], p[2 * i + 1]);
    uint32_t qx[8];
#pragma unroll
    for (int i = 0; i < 8; ++i) qx[i] = __shfl_xor(pw[i], 32);
    uint32_t wd[8];
    wd[0] = hi ? qx[2] : pw[0];  // keys (0,1) | (8,9)
    wd[1] = hi ? qx[3] : pw[1];  // keys (2,3) | (10,11)
    wd[2] = hi ? pw[2] : qx[0];  // keys (4,5) | (12,13)
    wd[3] = hi ? pw[3] : qx[1];  // keys (6,7) | (14,15)
    wd[4] = hi ? qx[6] : pw[4];  // keys (16,17) | (24,25)
    wd[5] = hi ? qx[7] : pw[5];  // keys (18,19) | (26,27)
    wd[6] = hi ? pw[6] : qx[4];  // keys (20,21) | (28,29)
    wd[7] = hi ? pw[7] : qx[5];  // keys (22,23) | (30,31)
    bf16x8 pa0, pa1;
    __builtin_memcpy(&pa0, &wd[0], 16);
    __builtin_memcpy(&pa1, &wd[4], 16);

    // Y[q][d] += P V
    yacc0 = __builtin_amdgcn_mfma_f32_32x32x16_bf16(pa0, vf[0], yacc0, 0, 0, 0);
    yacc0 = __builtin_amdgcn_mfma_f32_32x32x16_bf16(pa1, vf[2], yacc0, 0, 0, 0);
    yacc1 = __builtin_amdgcn_mfma_f32_32x32x16_bf16(pa0, vf[1], yacc1, 0, 0, 0);
    yacc1 = __builtin_amdgcn_mfma_f32_32x32x16_bf16(pa1, vf[3], yacc1, 0, 0, 0);
  }

  // epilogue: rows are queries now; fetch 1/l per row via shfl
  float linv = 1.0f / l;
#pragma unroll
  for (int r = 0; r < 16; ++r) {
    int rq = (r & 3) + 8 * (r >> 2) + 4 * hi;
    float rl = __shfl(linv, rq);
    size_t o = ((size_t)(b * Sc + qw + rq) << 10) + h * 64;
    out[o + col] = yacc0[r] * rl;
    out[o + 32 + col] = yacc1[r] * rl;
  }
}

extern "C" void kernel_launch(void* const* d_in, const int* in_sizes, int n_in,
                              void* d_out, int out_size, void* d_ws, size_t ws_size,
                              hipStream_t stream) {
  const float* x  = (const float*)d_in[0];
  const int* mask = (const int*)d_in[1];
  const float* Wq = (const float*)d_in[2];
  const float* bq = (const float*)d_in[3];
  const float* Wk = (const float*)d_in[4];
  const float* bk = (const float*)d_in[5];
  const float* Wv = (const float*)d_in[6];
  const float* bv = (const float*)d_in[7];
  float* out = (float*)d_out;

  char* ws = (char*)d_ws;
  const size_t SZ_XB = (size_t)8192 * 1024 * 2;      // 16 MiB bf16 x
  const size_t SZ_WT = (size_t)3 * 1024 * 1024 * 2;  // 6 MiB bf16 W^T
  const size_t SZ_T  = (size_t)8192 * 1024 * 2;      // 16 MiB each Q/K/V/Vt
  u16* xb  = (u16*)ws;
  u16* wt  = (u16*)(ws + SZ_XB);
  u16* qb  = (u16*)(ws + SZ_XB + SZ_WT);
  u16* kb  = (u16*)(ws + SZ_XB + SZ_WT + SZ_T);
  u16* vb  = (u16*)(ws + SZ_XB + SZ_WT + 2 * SZ_T);
  u16* vtb = (u16*)(ws + SZ_XB + SZ_WT + 3 * SZ_T);

  cast_x_kernel<<<8192, 256, 0, stream>>>(x, xb, 8192 * 1024 / 4);
  cast_wt_kernel<<<768, 256, 0, stream>>>(Wq, Wk, Wv, wt);
  qkv_gemm_kernel<<<1536, 256, 0, stream>>>(xb, wt, bq, bk, bv, qb, kb, vb);
  vtrans_kernel<<<2048, 256, 0, stream>>>(vb, vtb);
  attn_kernel<<<1024, 256, 0, stream>>>(qb, kb, vtb, mask, out);
}